// Round 3
// baseline (229.617 us; speedup 1.0000x reference)
//
#include <hip/hip_runtime.h>

// DepthToSpace: in [8, 64, 256, 256] f32 -> out [8, 4, 1024, 1024] f32
// out[b, s, h*4+r, w*4+c] = in[b, s*16 + r*4 + c, h, w]
//
// One block per (b, s, h-pair): loads 16 channels x 2 rows (2 KB contiguous
// per channel stream, vs 1 KB before - DRAM burst efficiency), stages 32 KB
// in LDS, writes 8 output rows = 32 KB contiguous. All global traffic is
// dwordx4 both directions; LDS gather is 2-lanes/bank (free on gfx950).
// Occupancy: 32 KB LDS -> 5 blocks/CU = 20 waves/CU.

#define CH_STRIDE 65536  // H*W floats

__global__ __launch_bounds__(256) void DepthToSpace_8486855377460_kernel(
    const float* __restrict__ in, float* __restrict__ out) {
    __shared__ float lds[16 * 512];  // 32 KB: [ch within group][row_in_pair*256 + w]

    int t = threadIdx.x;           // 0..255
    int idx = blockIdx.x;          // ((b*4)+s)*128 + h2
    int h2 = idx & 127;            // h-pair index; h0 = 2*h2
    int s  = (idx >> 7) & 3;
    int b  = idx >> 9;
    int h0 = h2 << 1;

    const float* src = in + ((size_t)(b * 64 + s * 16)) * CH_STRIDE + h0 * 256;

    // Load: 16 ch x 512 floats = 2048 float4 across 256 threads (8 each).
    // j = k*256 + t; ch = j>>7 (wave-uniform), rem = j&127 -> each wave loads
    // a contiguous 1 KiB run; consecutive k continue the same channel's run.
#pragma unroll
    for (int k = 0; k < 8; ++k) {
        int j = k * 256 + t;
        int ch = j >> 7;           // 0..15
        int rem = j & 127;         // float4 index within the 2-row run
        float4 v = *(const float4*)(src + ch * CH_STRIDE + rem * 4);
        *(float4*)(&lds[ch * 512 + rem * 4]) = v;
    }

    __syncthreads();

    // Store: 8 output rows hh = 4*(h0 + rp) + r, rp = row-in-pair, r = 0..3.
    // Thread t writes float4 at ww = 4t: component c comes from channel
    // ch_local = r*4+c, input row rp, w = t.
    float* dst = out + ((size_t)(b * 4 + s) * 1024 + (size_t)(h0 * 4)) * 1024;
#pragma unroll
    for (int rr = 0; rr < 8; ++rr) {
        int rp = rr >> 2;          // which input row of the pair
        int r  = rr & 3;           // intra-cell row
        int lbase = (r * 4) * 512 + rp * 256 + t;
        float4 v;
        v.x = lds[lbase + 0 * 512];
        v.y = lds[lbase + 1 * 512];
        v.z = lds[lbase + 2 * 512];
        v.w = lds[lbase + 3 * 512];
        ((float4*)(dst + (size_t)(rp * 4 + r) * 1024))[t] = v;
    }
}

extern "C" void kernel_launch(void* const* d_in, const int* in_sizes, int n_in,
                              void* d_out, int out_size, void* d_ws, size_t ws_size,
                              hipStream_t stream) {
    const float* x = (const float*)d_in[0];
    float* out = (float*)d_out;
    dim3 block(256);
    dim3 grid(8 * 4 * 128);  // one block per (b, s, h-pair) = 4096 blocks
    DepthToSpace_8486855377460_kernel<<<grid, block, 0, stream>>>(x, out);
}